// Round 2
// baseline (703.741 us; speedup 1.0000x reference)
//
#include <hip/hip_runtime.h>

#define HH 512
#define WW 512
#define CC 3
#define PADDIM 544                      // 512 + 2*16
#define PADELEMS (CC * PADDIM * PADDIM) // 887808
#define NB 128                          // kernel blocks per dim
#define KSTR 16384                      // 128*128 stride between taps

// ---------------- pad kernel: edge-replicate into workspace ----------------
__global__ __launch_bounds__(256) void pad_kernel(const float* __restrict__ img,
                                                  float* __restrict__ pad) {
    int idx = blockIdx.x * 256 + threadIdx.x;
    if (idx >= PADELEMS) return;
    int c  = idx / (PADDIM * PADDIM);
    int r  = idx - c * (PADDIM * PADDIM);
    int py = r / PADDIM;
    int px = r - py * PADDIM;
    int iy = min(max(py - 16, 0), HH - 1);
    int ix = min(max(px - 16, 0), WW - 1);
    pad[idx] = img[(c * HH + iy) * WW + ix];
}

// ---------------- main kernel ----------------
// Grid = 3 channels x 128 h x 2 w-tiles = 768 blocks of 256 threads.
// Thread -> (c, y=4h+dy, wb): computes out[c][y][4wb..4wb+3] over all 33 u.
// No atomics: channels are disjoint. Register double-buffer across u: issue
// iteration u+1's 33 weight loads + 9 float4 row loads BEFORE iteration u's
// 396 FMAs, so the in-order wave overlaps full load latency with compute.
// __launch_bounds__(256,3): VGPR cap 168 fits wv[2][33]+row[2][36]+acc+addr.
template <bool PADDED>
__global__ __launch_bounds__(256, 3) void reblur_kernel(const float* __restrict__ src,
                                                        const float* __restrict__ Kern,
                                                        float* __restrict__ out) {
    const int lane = threadIdx.x & 63;
    const int dy   = threadIdx.x >> 6;       // wave-uniform
    const int c    = blockIdx.x >> 8;        // 0..2
    const int bb   = blockIdx.x & 255;
    const int h    = bb >> 1;                // 0..127
    const int wt   = bb & 1;                 // 0..1
    const int wb   = wt * 64 + lane;         // 0..127
    const int y    = 4 * h + dy;

    // uniform scalar base for weights; + lane per thread
    const float* ksl  = Kern + h * NB + wt * 64;
    const float* srcc = src + (PADDED ? c * (PADDIM * PADDIM) : c * (HH * WW));

    float acc[4] = {0.f, 0.f, 0.f, 0.f};
    float wv[2][33];
    float row[2][36];

    // ---- prologue: load u = 0 into buffer 0 ----
#pragma unroll
    for (int v = 0; v < 33; ++v) wv[0][v] = ksl[v * KSTR + lane];
    if (PADDED) {
        const float* rb = srcc + (y + 0) * PADDIM + 4 * wb;
#pragma unroll
        for (int j = 0; j < 9; ++j) {
            const float4 t = *reinterpret_cast<const float4*>(rb + 4 * j);
            row[0][4 * j + 0] = t.x;
            row[0][4 * j + 1] = t.y;
            row[0][4 * j + 2] = t.z;
            row[0][4 * j + 3] = t.w;
        }
    } else {
        const int iy = min(max(y - 16, 0), HH - 1);
#pragma unroll
        for (int e = 0; e < 36; ++e) {
            const int ix = min(max(4 * wb + e - 16, 0), WW - 1);
            row[0][e]    = srcc[iy * WW + ix];
        }
    }

    // ---- steady state: prefetch u+1 while computing u ----
#pragma unroll 2
    for (int u = 0; u < 33; ++u) {
        const int cur = u & 1;
        const int nxt = cur ^ 1;
        if (u < 32) {
            const int un = u + 1;
#pragma unroll
            for (int v = 0; v < 33; ++v) wv[nxt][v] = ksl[(un * 33 + v) * KSTR + lane];
            if (PADDED) {
                const float* rb = srcc + (y + un) * PADDIM + 4 * wb;
#pragma unroll
                for (int j = 0; j < 9; ++j) {
                    const float4 t = *reinterpret_cast<const float4*>(rb + 4 * j);
                    row[nxt][4 * j + 0] = t.x;
                    row[nxt][4 * j + 1] = t.y;
                    row[nxt][4 * j + 2] = t.z;
                    row[nxt][4 * j + 3] = t.w;
                }
            } else {
                const int iy = min(max(y + un - 16, 0), HH - 1);
#pragma unroll
                for (int e = 0; e < 36; ++e) {
                    const int ix = min(max(4 * wb + e - 16, 0), WW - 1);
                    row[nxt][e]  = srcc[iy * WW + ix];
                }
            }
        }
#pragma unroll
        for (int v = 0; v < 33; ++v) {
            const float wgt = wv[cur][v];
#pragma unroll
            for (int oj = 0; oj < 4; ++oj)
                acc[oj] = fmaf(row[cur][v + oj], wgt, acc[oj]);
        }
    }

    float4 o;
    o.x = acc[0]; o.y = acc[1]; o.z = acc[2]; o.w = acc[3];
    *reinterpret_cast<float4*>(out + (c * HH + y) * WW + 4 * wb) = o;
}

extern "C" void kernel_launch(void* const* d_in, const int* in_sizes, int n_in,
                              void* d_out, int out_size, void* d_ws, size_t ws_size,
                              hipStream_t stream) {
    const float* img  = (const float*)d_in[0];
    const float* Kern = (const float*)d_in[1];
    float* out        = (float*)d_out;

    if (ws_size >= (size_t)PADELEMS * sizeof(float)) {
        float* pad = (float*)d_ws;
        pad_kernel<<<(PADELEMS + 255) / 256, 256, 0, stream>>>(img, pad);
        reblur_kernel<true><<<768, 256, 0, stream>>>(pad, Kern, out);
    } else {
        reblur_kernel<false><<<768, 256, 0, stream>>>(img, Kern, out);
    }
}

// Round 3
// 150.073 us; speedup vs baseline: 4.6893x; 4.6893x over previous
//
#include <hip/hip_runtime.h>

#define HH 512
#define WW 512
#define PADDIM 544                      // 512 + 2*16
#define PADELEMS (3 * PADDIM * PADDIM)  // 887808
#define NB 128
#define KSTR 16384                      // 128*128 floats between taps

// ---------------- pad kernel: edge-replicate into workspace ----------------
__global__ __launch_bounds__(256) void pad_kernel(const float* __restrict__ img,
                                                  float* __restrict__ pad) {
    int idx = blockIdx.x * 256 + threadIdx.x;
    if (idx >= PADELEMS) return;
    int c  = idx / (PADDIM * PADDIM);
    int r  = idx - c * (PADDIM * PADDIM);
    int py = r / PADDIM;
    int px = r - py * PADDIM;
    int iy = min(max(py - 16, 0), HH - 1);
    int ix = min(max(px - 16, 0), WW - 1);
    pad[idx] = img[(c * HH + iy) * WW + ix];
}

// ---- async global->LDS helpers (wave-uniform LDS base + lane*size dest) ----
__device__ __forceinline__ void async4(const float* g, float* l) {
    __builtin_amdgcn_global_load_lds((const __attribute__((address_space(1))) void*)g,
                                     (__attribute__((address_space(3))) void*)l, 4, 0, 0);
}
__device__ __forceinline__ void async16(const float* g, float* l) {
    __builtin_amdgcn_global_load_lds((const __attribute__((address_space(1))) void*)g,
                                     (__attribute__((address_space(3))) void*)l, 16, 0, 0);
}

// ---------------- main kernel ----------------
// Grid = 2 u-halves x 128 h x 2 wt = 512 blocks (2/CU) of 256 threads (4 waves = dy).
// Weights K[u,v,h,wb0..wb0+63] staged to LDS (double-buffered, 33 x 256 B per u);
// image rows staged to an 8-slot/channel LDS ring (1 new row x 3c per u).
// Pipeline per iter: s_waitcnt vmcnt(0); s_barrier; issue u+1 stages; compute u.
// Loads get a full compute iteration to land -> steady-state stall ~0.
// All register arrays constant-indexed (round-2 spill lesson); dynamic indices
// (u&1 buf, ring slot) live on LDS addresses only.
__global__ __launch_bounds__(256, 2) void reblur_lds(const float* __restrict__ pad,
                                                     const float* __restrict__ Kern,
                                                     float* __restrict__ out) {
    __shared__ float s_w[2][33][64];    // 16.9 KB
    __shared__ float s_img[3][8][288];  // 27.6 KB

    const int lane = threadIdx.x & 63;
    const int dy   = threadIdx.x >> 6;        // wave id, uniform
    const int half = blockIdx.x >> 8;         // u-range half
    const int bb   = blockIdx.x & 255;
    const int h    = bb >> 1;                 // 0..127
    const int wt   = bb & 1;                  // 0..1
    const int wb   = wt * 64 + lane;
    const int y    = 4 * h + dy;
    const int u0   = half ? 17 : 0;
    const int u1   = half ? 33 : 17;

    const int kofs = h * NB + wt * 64 + lane; // per-lane weight offset within one tap

    // ---- prologue: stage weights(u0) + image rows [4h+u0 .. 4h+u0+3] x 3c ----
    for (int v = dy; v < 33; v += 4)
        async4(Kern + (u0 * 33 + v) * KSTR + kofs, &s_w[u0 & 1][v][0]);
    {
        const int p0 = 4 * h + u0;
        for (int k = dy; k < 12; k += 4) {     // wave dy stages row p0+dy of each c
            const int c = k >> 2;
            const int p = p0 + (k & 3);
            const float* gb = pad + (c * PADDIM + p) * PADDIM + 256 * wt;
            float* lb = &s_img[c][p & 7][0];
            async16(gb + 4 * lane, lb);                       // floats 0..255
            if (lane < 8) async16(gb + 256 + 4 * lane, lb + 256); // floats 256..287
        }
    }

    float acc[3][4];
#pragma unroll
    for (int c = 0; c < 3; ++c)
#pragma unroll
        for (int oj = 0; oj < 4; ++oj) acc[c][oj] = 0.f;

#pragma unroll 1
    for (int u = u0; u < u1; ++u) {
        // wait my staged loads for iter u; barrier -> everyone's arrived and
        // everyone is done reading the LDS regions iter u+1 will overwrite
        asm volatile("s_waitcnt vmcnt(0)" ::: "memory");
        __builtin_amdgcn_s_barrier();
        asm volatile("" ::: "memory");

        // ---- issue stages for u+1 (fire-and-forget) ----
        if (u + 1 < u1) {
            const int ku = u + 1;
            for (int v = dy; v < 33; v += 4)
                async4(Kern + (ku * 33 + v) * KSTR + kofs, &s_w[ku & 1][v][0]);
            if (dy < 3) {
                const int c = dy;
                const int p = 4 * h + u + 4;   // new row for iter u+1
                const float* gb = pad + (c * PADDIM + p) * PADDIM + 256 * wt;
                float* lb = &s_img[c][p & 7][0];
                async16(gb + 4 * lane, lb);
                if (lane < 8) async16(gb + 256 + 4 * lane, lb + 256);
            }
        }

        // ---- compute iter u from LDS ----
        float wv[33];
#pragma unroll
        for (int v = 0; v < 33; ++v) wv[v] = s_w[u & 1][v][lane];
        const int slot = (4 * h + u + dy) & 7;
#pragma unroll
        for (int c = 0; c < 3; ++c) {
            const float4* rp = (const float4*)&s_img[c][slot][4 * lane];
            float row[36];
#pragma unroll
            for (int j = 0; j < 9; ++j) {
                const float4 t = rp[j];
                row[4 * j + 0] = t.x;
                row[4 * j + 1] = t.y;
                row[4 * j + 2] = t.z;
                row[4 * j + 3] = t.w;
            }
#pragma unroll
            for (int v = 0; v < 33; ++v)
#pragma unroll
                for (int oj = 0; oj < 4; ++oj)
                    acc[c][oj] = fmaf(row[v + oj], wv[v], acc[c][oj]);
        }
    }

    // ---- epilogue: combine the two u-halves via device-scope f32 atomics ----
#pragma unroll
    for (int c = 0; c < 3; ++c) {
        float* op = out + (c * HH + y) * WW + 4 * wb;
#pragma unroll
        for (int oj = 0; oj < 4; ++oj) atomicAdd(op + oj, acc[c][oj]);
    }
}

// ---------------- fallback (ws too small): naive but correct ----------------
__global__ __launch_bounds__(256) void reblur_naive(const float* __restrict__ img,
                                                    const float* __restrict__ Kern,
                                                    float* __restrict__ out) {
    const int lane = threadIdx.x & 63;
    const int dy   = threadIdx.x >> 6;
    const int c    = blockIdx.x >> 8;
    const int bb   = blockIdx.x & 255;
    const int h    = bb >> 1;
    const int wt   = bb & 1;
    const int wb   = wt * 64 + lane;
    const int y    = 4 * h + dy;

    float acc[4] = {0.f, 0.f, 0.f, 0.f};
    const float* kb = Kern + h * NB + wb;
#pragma unroll 1
    for (int u = 0; u < 33; ++u) {
        const int iy = min(max(y + u - 16, 0), HH - 1);
        float row[36];
#pragma unroll
        for (int e = 0; e < 36; ++e) {
            const int ix = min(max(4 * wb + e - 16, 0), WW - 1);
            row[e]       = img[(c * HH + iy) * WW + ix];
        }
#pragma unroll
        for (int v = 0; v < 33; ++v) {
            const float w = kb[(u * 33 + v) * KSTR];
#pragma unroll
            for (int oj = 0; oj < 4; ++oj)
                acc[oj] = fmaf(row[v + oj], w, acc[oj]);
        }
    }
    float4 o;
    o.x = acc[0]; o.y = acc[1]; o.z = acc[2]; o.w = acc[3];
    *reinterpret_cast<float4*>(out + (c * HH + y) * WW + 4 * wb) = o;
}

extern "C" void kernel_launch(void* const* d_in, const int* in_sizes, int n_in,
                              void* d_out, int out_size, void* d_ws, size_t ws_size,
                              hipStream_t stream) {
    const float* img  = (const float*)d_in[0];
    const float* Kern = (const float*)d_in[1];
    float* out        = (float*)d_out;

    if (ws_size >= (size_t)PADELEMS * sizeof(float)) {
        float* pad = (float*)d_ws;
        // u-halves accumulate via atomicAdd -> zero output first
        hipMemsetAsync(d_out, 0, (size_t)out_size * sizeof(float), stream);
        pad_kernel<<<(PADELEMS + 255) / 256, 256, 0, stream>>>(img, pad);
        reblur_lds<<<512, 256, 0, stream>>>(pad, Kern, out);
    } else {
        reblur_naive<<<768, 256, 0, stream>>>(img, Kern, out);
    }
}